// Round 11
// baseline (313.465 us; speedup 1.0000x reference)
//
#include <hip/hip_runtime.h>

#define KOFF 27
#define MPAIR 100000
#define NPAIR (KOFF * MPAIR)        // 2,700,000
#define NIN 200000
#define NOUT 400000
#define CIN 32
#define COUT 32

#define ROWS_PER_BIN 256
#define NBIN ((NOUT + ROWS_PER_BIN - 1) / ROWS_PER_BIN)   // 1563
#define CAPB 3072                   // per-bin capacity (avg 1728, +32 sigma)
#define BPB 8192                    // pairs per bin_kernel block
#define SPILL_CAP 65536

// ---------- workspace layout (bytes) ----------
// gbin      @ 0          : NBIN*4 -> pad 8192
// spill_cnt @ 8192       : 256
// spill     @ 8448       : SPILL_CAP*8 = 524,288        -> end 532,736
// binned    @ 532,736    : NBIN*CAPB*4 = 19,206,144     -> end 19,738,880
// per_off   @ 19,738,880 : 2.7M*32*2  = 172,800,000     -> end 192,538,880
// feats16   @ 192,538,880: 200000*32*2 = 12,800,000     -> end 205,338,880
#define O_SPCNT   ((size_t)8192)
#define O_SPILL   ((size_t)8448)
#define O_BINNED  ((size_t)532736)
#define O_PEROFF  ((size_t)19738880)
#define O_F16     ((size_t)192538880)
#define WS_NEED   ((size_t)205338880)

typedef unsigned int uint4n __attribute__((ext_vector_type(4)));

__device__ __forceinline__ unsigned int bf16pair(float a, float b) {
    unsigned int ua = __float_as_uint(a), ub = __float_as_uint(b);
    ua = (ua + 0x7fffu + ((ua >> 16) & 1u)) >> 16;   // RNE
    ub = (ub + 0x7fffu + ((ub >> 16) & 1u)) >> 16;
    return ua | (ub << 16);
}
__device__ __forceinline__ float bf2f(unsigned short v) {
    return __uint_as_float(((unsigned int)v) << 16);
}
__device__ __forceinline__ float bf2f_lo(unsigned int w) {
    return __uint_as_float(w << 16);
}
__device__ __forceinline__ float bf2f_hi(unsigned int w) {
    return __uint_as_float(w & 0xFFFF0000u);
}

// ---------- Phase 0: feats f32 -> bf16 ----------
__global__ __launch_bounds__(256) void cvt_kernel(
    const float* __restrict__ feats, unsigned short* __restrict__ f16)
{
    int i = blockIdx.x * 256 + threadIdx.x;          // one thread = 8 elements
    if (i >= NIN * CIN / 8) return;
    const float4* src = reinterpret_cast<const float4*>(feats) + i * 2;
    float4 a = src[0], b = src[1];
    uint4n u;
    u.x = bf16pair(a.x, a.y); u.y = bf16pair(a.z, a.w);
    u.z = bf16pair(b.x, b.y); u.w = bf16pair(b.z, b.w);
    reinterpret_cast<uint4n*>(f16)[i] = u;
}

// ---------- Phase 1: multisplit pair ids by output-row bin ----------
__global__ __launch_bounds__(256) void bin_kernel(
    const int* __restrict__ out_map,
    int* __restrict__ gbin, int* __restrict__ binned,
    int* __restrict__ spill_cnt, int2* __restrict__ spill)
{
    __shared__ int lhist[NBIN];              // count, then running cursor
    const int t = threadIdx.x;
    const int base = blockIdx.x * BPB;

    for (int c = t; c < NBIN; c += 256) lhist[c] = 0;
    __syncthreads();

    for (int i = t; i < BPB; i += 256) {
        int p = base + i;
        if (p < NPAIR) atomicAdd(&lhist[out_map[p] >> 8], 1);
    }
    __syncthreads();

    for (int c = t; c < NBIN; c += 256) {
        int cnt = lhist[c];
        lhist[c] = (cnt > 0) ? atomicAdd(&gbin[c], cnt) : 0;  // chunk base
    }
    __syncthreads();

    for (int i = t; i < BPB; i += 256) {
        int p = base + i;
        if (p >= NPAIR) continue;
        int row = out_map[p];
        int bin = row >> 8;
        int val = ((row & 255) << 22) | p;
        int pos = atomicAdd(&lhist[bin], 1);
        if (pos < CAPB) {
            binned[(size_t)bin * CAPB + pos] = val;
        } else {
            int o = atomicAdd(spill_cnt, 1);
            if (o < SPILL_CAP) spill[o] = make_int2(row, p);
        }
    }
}

// ---------- Phase 2: ILP2 matvec — 2 pairs/thread (same k), MLP-8 gather ----------
__global__ __launch_bounds__(256) void mv_kernel(
    const unsigned short* __restrict__ f16, const float* __restrict__ weight,
    const int* __restrict__ in_map, unsigned short* __restrict__ per_off)
{
    const int k = blockIdx.y;                 // wave-uniform -> SGPR weights
    const int m0 = blockIdx.x * 256 + threadIdx.x;   // [0, MPAIR/2)
    if (m0 >= MPAIR / 2) return;
    const int p0 = k * MPAIR + m0;
    const int p1 = p0 + MPAIR / 2;

    const int r0 = in_map[p0];
    const int r1 = in_map[p1];

    // issue all 8 independent 16B loads -> MLP 8
    const uint4n* fa = reinterpret_cast<const uint4n*>(f16 + (size_t)r0 * CIN);
    const uint4n* fb = reinterpret_cast<const uint4n*>(f16 + (size_t)r1 * CIN);
    uint4n qa0 = fa[0], qa1 = fa[1], qa2 = fa[2], qa3 = fa[3];
    uint4n qb0 = fb[0], qb1 = fb[1], qb2 = fb[2], qb3 = fb[3];

    float accA[COUT], accB[COUT];
#pragma unroll
    for (int i = 0; i < COUT; ++i) { accA[i] = 0.f; accB[i] = 0.f; }

    const float* wk = weight + (size_t)k * (CIN * COUT);

    // process 8 channels per q-register-pair; weight value shared by both pairs
#define DO8(QA, QB, CI0)                                                    \
    {                                                                       \
        float fA[8], fB[8];                                                 \
        fA[0] = bf2f_lo(QA.x); fA[1] = bf2f_hi(QA.x);                       \
        fA[2] = bf2f_lo(QA.y); fA[3] = bf2f_hi(QA.y);                       \
        fA[4] = bf2f_lo(QA.z); fA[5] = bf2f_hi(QA.z);                       \
        fA[6] = bf2f_lo(QA.w); fA[7] = bf2f_hi(QA.w);                       \
        fB[0] = bf2f_lo(QB.x); fB[1] = bf2f_hi(QB.x);                       \
        fB[2] = bf2f_lo(QB.y); fB[3] = bf2f_hi(QB.y);                       \
        fB[4] = bf2f_lo(QB.z); fB[5] = bf2f_hi(QB.z);                       \
        fB[6] = bf2f_lo(QB.w); fB[7] = bf2f_hi(QB.w);                       \
        _Pragma("unroll")                                                   \
        for (int j = 0; j < 8; ++j) {                                       \
            _Pragma("unroll")                                               \
            for (int co = 0; co < COUT; ++co) {                             \
                float w = wk[(CI0 + j) * COUT + co];                        \
                accA[co] = fmaf(fA[j], w, accA[co]);                        \
                accB[co] = fmaf(fB[j], w, accB[co]);                        \
            }                                                               \
        }                                                                   \
    }

    DO8(qa0, qb0, 0)
    DO8(qa1, qb1, 8)
    DO8(qa2, qb2, 16)
    DO8(qa3, qb3, 24)
#undef DO8

    uint4n u;
    uint4n* dstA = reinterpret_cast<uint4n*>(per_off + (size_t)p0 * COUT);
#pragma unroll
    for (int j = 0; j < 4; ++j) {
        u.x = bf16pair(accA[8 * j + 0], accA[8 * j + 1]);
        u.y = bf16pair(accA[8 * j + 2], accA[8 * j + 3]);
        u.z = bf16pair(accA[8 * j + 4], accA[8 * j + 5]);
        u.w = bf16pair(accA[8 * j + 6], accA[8 * j + 7]);
        dstA[j] = u;
    }
    uint4n* dstB = reinterpret_cast<uint4n*>(per_off + (size_t)p1 * COUT);
#pragma unroll
    for (int j = 0; j < 4; ++j) {
        u.x = bf16pair(accB[8 * j + 0], accB[8 * j + 1]);
        u.y = bf16pair(accB[8 * j + 2], accB[8 * j + 3]);
        u.z = bf16pair(accB[8 * j + 4], accB[8 * j + 5]);
        u.w = bf16pair(accB[8 * j + 6], accB[8 * j + 7]);
        dstB[j] = u;
    }
}

// ---------- Phase 3: per-bin counting-sort (register-staged) + ILP4 gather ----------
__global__ __launch_bounds__(256) void gather3_kernel(
    const unsigned short* __restrict__ per_off,
    const int* __restrict__ gbin, const int* __restrict__ binned,
    float* __restrict__ out)
{
    __shared__ int sorted[CAPB];             // 12 KB
    __shared__ int cnt[ROWS_PER_BIN];
    __shared__ int scn[ROWS_PER_BIN];
    __shared__ int cur[ROWS_PER_BIN];

    const int bin = blockIdx.x;
    const int t = threadIdx.x;
    const int n = min(gbin[bin], CAPB);
    const int* mybin = binned + (size_t)bin * CAPB;

    cnt[t] = 0;
    __syncthreads();

    // single coalesced read, staged in registers (<=12 per thread)
    int rc[12];
    int nmine = 0;
    for (int i = t; i < n; i += 256) {
        int v = mybin[i];
        rc[nmine++] = v;
        atomicAdd(&cnt[(v >> 22) & 255], 1);
    }
    __syncthreads();

    scn[t] = cnt[t];
    __syncthreads();
#pragma unroll
    for (int off = 1; off < 256; off <<= 1) {
        int v = (t >= off) ? scn[t - off] : 0;
        __syncthreads();
        scn[t] += v;
        __syncthreads();
    }
    cur[t] = scn[t] - cnt[t];
    __syncthreads();

    for (int j = 0; j < nmine; ++j) {
        int v = rc[j];
        int pos = atomicAdd(&cur[(v >> 22) & 255], 1);
        sorted[pos] = v & 0x3FFFFF;
    }
    __syncthreads();

    const int g = t >> 5, lane = t & 31;
    for (int r = g; r < ROWS_PER_BIN; r += 8) {
        int grow = (bin << 8) + r;
        if (grow >= NOUT) break;
        int s1 = scn[r], s0 = s1 - cnt[r];
        float a0 = 0.f, a1 = 0.f, a2 = 0.f, a3 = 0.f;
        int i = s0;
        for (; i + 4 <= s1; i += 4) {
            int p0 = sorted[i], p1 = sorted[i + 1], p2 = sorted[i + 2], p3 = sorted[i + 3];
            a0 += bf2f(per_off[(size_t)p0 * COUT + lane]);
            a1 += bf2f(per_off[(size_t)p1 * COUT + lane]);
            a2 += bf2f(per_off[(size_t)p2 * COUT + lane]);
            a3 += bf2f(per_off[(size_t)p3 * COUT + lane]);
        }
        for (; i < s1; ++i)
            a0 += bf2f(per_off[(size_t)sorted[i] * COUT + lane]);
        out[(size_t)grow * COUT + lane] = (a0 + a1) + (a2 + a3);
    }
}

// ---------- Phase 4: statistically-rare bin overflow, recompute + atomics ----------
__global__ __launch_bounds__(256) void spill_kernel(
    const float* __restrict__ feats, const float* __restrict__ weight,
    const int* __restrict__ in_map,
    const int* __restrict__ spill_cnt, const int2* __restrict__ spill,
    float* __restrict__ out)
{
    int n = min(*spill_cnt, SPILL_CAP);
    for (int i = blockIdx.x * blockDim.x + threadIdx.x; i < n * 32;
         i += gridDim.x * blockDim.x) {
        int idx = i >> 5, co = i & 31;
        int2 s = spill[idx];
        int row = s.x;
        int p   = s.y;
        int k   = p / MPAIR;
        int irow = in_map[p];
        const float* f  = feats + (size_t)irow * CIN;
        const float* wk = weight + (size_t)k * (CIN * COUT);
        float acc = 0.f;
#pragma unroll
        for (int ci = 0; ci < CIN; ++ci)
            acc = fmaf(f[ci], wk[ci * COUT + co], acc);
        atomicAdd(&out[(size_t)row * COUT + co], acc);
    }
}

// ---------- last-resort fallback (tiny ws): R1 atomic scatter ----------
__global__ __launch_bounds__(256) void spconvt_fallback(
    const float* __restrict__ feats, const float* __restrict__ weight,
    const int* __restrict__ in_map, const int* __restrict__ out_map,
    float* __restrict__ out)
{
    const int k = blockIdx.y;
    const int m = blockIdx.x * blockDim.x + threadIdx.x;
    const bool active = (m < MPAIR);
    const int mm = active ? m : (MPAIR - 1);
    const int pair = k * MPAIR + mm;
    const int in_row = in_map[pair];
    const int out_row = out_map[pair];
    const float4* frow = reinterpret_cast<const float4*>(feats + (size_t)in_row * CIN);
    float4 f4[8];
#pragma unroll
    for (int i = 0; i < 8; ++i) f4[i] = frow[i];
    const float* f = reinterpret_cast<const float*>(f4);
    float acc[COUT];
#pragma unroll
    for (int i = 0; i < COUT; ++i) acc[i] = 0.f;
    const float* wk = weight + (size_t)k * (CIN * COUT);
#pragma unroll
    for (int ci = 0; ci < CIN; ++ci) {
        const float fv = f[ci];
#pragma unroll
        for (int co = 0; co < COUT; ++co)
            acc[co] = fmaf(fv, wk[ci * COUT + co], acc[co]);
    }
    if (active) {
        float* orow = out + (size_t)out_row * COUT;
#pragma unroll
        for (int co = 0; co < COUT; ++co) atomicAdd(orow + co, acc[co]);
    }
}

extern "C" void kernel_launch(void* const* d_in, const int* in_sizes, int n_in,
                              void* d_out, int out_size, void* d_ws, size_t ws_size,
                              hipStream_t stream) {
    const float* feats  = (const float*)d_in[0];
    const float* weight = (const float*)d_in[1];
    const int* in_map   = (const int*)d_in[2];
    const int* out_map  = (const int*)d_in[3];
    float* out          = (float*)d_out;
    char* ws            = (char*)d_ws;

    if (ws_size >= WS_NEED) {
        int* gbin               = (int*)(ws);
        int* spill_cnt          = (int*)(ws + O_SPCNT);
        int2* spill             = (int2*)(ws + O_SPILL);
        int* binned             = (int*)(ws + O_BINNED);
        unsigned short* per_off = (unsigned short*)(ws + O_PEROFF);
        unsigned short* f16     = (unsigned short*)(ws + O_F16);

        (void)hipMemsetAsync(ws, 0, O_SPILL, stream);   // gbin + spill_cnt only

        cvt_kernel<<<dim3((NIN * CIN / 8 + 255) / 256), dim3(256), 0, stream>>>(
            feats, f16);

        bin_kernel<<<dim3((NPAIR + BPB - 1) / BPB), dim3(256), 0, stream>>>(
            out_map, gbin, binned, spill_cnt, spill);

        mv_kernel<<<dim3((MPAIR / 2 + 255) / 256, KOFF), dim3(256), 0, stream>>>(
            f16, weight, in_map, per_off);

        gather3_kernel<<<dim3(NBIN), dim3(256), 0, stream>>>(
            per_off, gbin, binned, out);

        spill_kernel<<<dim3(64), dim3(256), 0, stream>>>(
            feats, weight, in_map, spill_cnt, spill, out);
    } else {
        (void)hipMemsetAsync(d_out, 0, (size_t)out_size * sizeof(float), stream);
        spconvt_fallback<<<dim3((MPAIR + 255) / 256, KOFF), dim3(256), 0, stream>>>(
            feats, weight, in_map, out_map, out);
    }
}